// Round 1
// baseline (798.354 us; speedup 1.0000x reference)
//
#include <hip/hip_runtime.h>
#include <hip/hip_cooperative_groups.h>

namespace cg = cooperative_groups;

// MultiHeadSelfAttention: B=4 T=1024 H=8 D=64 N_UNITS=512, fp32 in/out.
// R4: single fused cooperative kernel (512 blocks x 256 thr, 2 blocks/CU).
// Phases: A cvtx+wtrans | B qkv | C pos-gemm (2 t-rows/block, barrier-free
// streaming) | D flash | E proj, separated by grid.sync(). Original 6-kernel
// pipeline kept as fallback if cooperative launch is unavailable.
// Fragment layouts (16x16x32_bf16): A/B = 8 contig k at row lane&15,
// k-offset (lane>>4)*8 ; C/D: col=lane&15, row=(lane>>4)*4+reg.

#define TT 1024
#define DH 64
#define NH 8
#define NU 512

typedef __bf16 bf16;
typedef bf16 bf16x8 __attribute__((ext_vector_type(8)));
typedef bf16 bf16x4 __attribute__((ext_vector_type(4)));
typedef float f32x4 __attribute__((ext_vector_type(4)));

#define MFMA16(a, b, c) __builtin_amdgcn_mfma_f32_16x16x32_bf16(a, b, c, 0, 0, 0)

// ======================= fallback kernels (verified R3 pipeline) =======================

__global__ __launch_bounds__(256) void cvtx_k(const float* __restrict__ x,
                                              bf16* __restrict__ xb) {
  int i = blockIdx.x * 256 + threadIdx.x;
  float4 v = ((const float4*)x)[i];
  bf16x4 o = {(bf16)v.x, (bf16)v.y, (bf16)v.z, (bf16)v.w};
  ((bf16x4*)xb)[i] = o;
}

__global__ __launch_bounds__(256) void wtrans_k(const float* __restrict__ Wq,
                                                const float* __restrict__ Wk,
                                                const float* __restrict__ Wv,
                                                const float* __restrict__ Wo,
                                                bf16* __restrict__ wt) {
  int n = blockIdx.x * 256 + threadIdx.x;
  int k0 = blockIdx.y * 8;
  int w = blockIdx.z;
  const float* W = (w == 0) ? Wq : (w == 1) ? Wk : (w == 2) ? Wv : Wo;
  bf16x8 v;
#pragma unroll
  for (int j = 0; j < 8; j++) v[j] = (bf16)W[(size_t)(k0 + j) * NU + n];
  *(bf16x8*)(wt + ((size_t)w * NU + n) * NU + k0) = v;
}

__global__ __launch_bounds__(256) void qkv_k(
    const bf16* __restrict__ xb, const bf16* __restrict__ wt,
    const float* __restrict__ bq, const float* __restrict__ bk,
    const float* __restrict__ bv, bf16* __restrict__ Qb, bf16* __restrict__ Kb,
    bf16* __restrict__ Vt) {
  int tid = threadIdx.x, wid = tid >> 6, ln = tid & 63;
  int n15 = ln & 15, qd = ln >> 4;
  int n0 = blockIdx.x * 64, m0 = blockIdx.y * 64;
  int mrow = m0 + wid * 16 + n15;

  const f32x4 fz = {0.f, 0.f, 0.f, 0.f};
  f32x4 acc[3][4];
#pragma unroll
  for (int w = 0; w < 3; w++)
#pragma unroll
    for (int nt = 0; nt < 4; nt++) acc[w][nt] = fz;

  for (int k0 = 0; k0 < NU; k0 += 32) {
    bf16x8 a = *(const bf16x8*)(xb + (size_t)mrow * NU + k0 + qd * 8);
#pragma unroll
    for (int w = 0; w < 3; w++)
#pragma unroll
      for (int nt = 0; nt < 4; nt++) {
        bf16x8 b = *(const bf16x8*)(wt + ((size_t)w * NU + n0 + nt * 16 + n15) * NU +
                                    k0 + qd * 8);
        acc[w][nt] = MFMA16(a, b, acc[w][nt]);
      }
  }

  int bb = m0 >> 10;
  int tbase = (m0 & 1023) + wid * 16 + qd * 4;
  int hh = n0 >> 6;
#pragma unroll
  for (int nt = 0; nt < 4; nt++) {
    int d = nt * 16 + n15;
    float bqv = bq[n0 + d], bkv = bk[n0 + d], bvv = bv[n0 + d];
    bf16x4 vv;
#pragma unroll
    for (int r = 0; r < 4; r++) {
      int t = tbase + r;
      size_t qk_idx = ((size_t)(bb * NH + hh) * TT + t) * DH + d;
      Qb[qk_idx] = (bf16)(acc[0][nt][r] + bqv);
      Kb[qk_idx] = (bf16)(acc[1][nt][r] + bkv);
      vv[r] = (bf16)(acc[2][nt][r] + bvv);
    }
    *(bf16x4*)(Vt + ((size_t)(bb * NH + hh) * DH + d) * TT + tbase) = vv;
  }
}

__global__ __launch_bounds__(256) void pos_gemm_k(const float* __restrict__ pos,
                                                  const bf16* __restrict__ Qb,
                                                  bf16* __restrict__ biasF) {
  int tid = threadIdx.x, wid = tid >> 6, ln = tid & 63;
  int n15 = ln & 15, qd = ln >> 4;
  int t = blockIdx.y;
  int s0b = blockIdx.x * 128;

  __shared__ bf16 Qs[32 * 72];
  {
    int bh = tid >> 3, dc = (tid & 7) * 8;
    *(bf16x8*)(&Qs[bh * 72 + dc]) =
        *(const bf16x8*)(Qb + ((size_t)bh * TT + t) * DH + dc);
  }
  __syncthreads();

  bf16x8 bQ[2][2];
#pragma unroll
  for (int bht = 0; bht < 2; bht++)
#pragma unroll
    for (int kc = 0; kc < 2; kc++)
      bQ[bht][kc] = *(const bf16x8*)(&Qs[(bht * 16 + n15) * 72 + kc * 32 + qd * 8]);

  const f32x4 fz = {0.f, 0.f, 0.f, 0.f};
  f32x4 acc[2][2];
#pragma unroll
  for (int stl = 0; stl < 2; stl++)
#pragma unroll
    for (int bht = 0; bht < 2; bht++) acc[stl][bht] = fz;

  int sw = s0b + wid * 32;
#pragma unroll
  for (int stl = 0; stl < 2; stl++) {
    const float* pr = pos + ((size_t)t * TT + sw + stl * 16 + n15) * DH + qd * 8;
#pragma unroll
    for (int kc = 0; kc < 2; kc++) {
      f32x4 u = __builtin_nontemporal_load((const f32x4*)(pr + kc * 32));
      f32x4 v = __builtin_nontemporal_load((const f32x4*)(pr + kc * 32 + 4));
      bf16x8 aP = {(bf16)u[0], (bf16)u[1], (bf16)u[2], (bf16)u[3],
                   (bf16)v[0], (bf16)v[1], (bf16)v[2], (bf16)v[3]};
#pragma unroll
      for (int bht = 0; bht < 2; bht++)
        acc[stl][bht] = MFMA16(aP, bQ[bht][kc], acc[stl][bht]);
    }
  }

  int t16 = t >> 4, tin = t & 15, s32 = (s0b >> 5) + wid;
#pragma unroll
  for (int bht = 0; bht < 2; bht++) {
    bf16x8 ov;
#pragma unroll
    for (int r = 0; r < 4; r++) {
      ov[r] = (bf16)acc[0][bht][r];
      ov[4 + r] = (bf16)acc[1][bht][r];
    }
    *(bf16x8*)(biasF +
               (((size_t)(bht * 16 + n15) * 64 + t16) * 32 + s32) * 512 +
               tin * 32 + qd * 8) = ov;
  }
}

__global__ __launch_bounds__(256) void flash_k(const bf16* __restrict__ Qb,
                                               const bf16* __restrict__ Kb,
                                               const bf16* __restrict__ Vt,
                                               const bf16* __restrict__ biasF,
                                               bf16* __restrict__ att) {
  int tid = threadIdx.x, wid = tid >> 6, ln = tid & 63;
  int n15 = ln & 15, qd = ln >> 4;
  int bh = blockIdx.x;
  int t0 = blockIdx.y * 64 + wid * 16;
  const float SC = 0.18033688f;  // log2(e)/8

  __shared__ bf16 Pl[4][16][40];

  bf16x8 bQ[2];
#pragma unroll
  for (int kc = 0; kc < 2; kc++)
    bQ[kc] = *(const bf16x8*)(Qb + ((size_t)bh * TT + t0 + n15) * DH + kc * 32 + qd * 8);

  const bf16* Kbase = Kb + (size_t)bh * TT * DH;
  const bf16* Vbase = Vt + (size_t)bh * DH * TT;
  const bf16* Fbase = biasF + (((size_t)bh * 64 + (t0 >> 4)) * 32) * 512 +
                      n15 * 32 + qd * 8;

  const f32x4 fz = {0.f, 0.f, 0.f, 0.f};
  f32x4 accO[4] = {fz, fz, fz, fz};
  f32x4 accL = fz;
  const bf16 one = (bf16)1.0f;
  const bf16x8 onesv = {one, one, one, one, one, one, one, one};

  bf16x8 Kf[2][4], Vf[2][4];
  bf16x8 Bf[4];

  auto ldKV = [&](int buf, int s0) {
#pragma unroll
    for (int mt = 0; mt < 2; mt++)
#pragma unroll
      for (int kc = 0; kc < 2; kc++)
        Kf[buf][mt * 2 + kc] =
            *(const bf16x8*)(Kbase + (size_t)(s0 + mt * 16 + n15) * DH + kc * 32 + qd * 8);
#pragma unroll
    for (int dt = 0; dt < 4; dt++)
      Vf[buf][dt] = *(const bf16x8*)(Vbase + (size_t)(dt * 16 + n15) * TT + s0 + qd * 8);
  };
  auto ldB = [&](int buf, int s0) {
    Bf[buf] = *(const bf16x8*)(Fbase + (size_t)(s0 >> 5) * 512);
  };

  ldB(0, 0);
  ldB(1, 32);
  ldKV(0, 0);

#pragma unroll 4
  for (int it = 0; it < 32; it++) {
    int s0 = it * 32;
    ldKV((it + 1) & 1, (s0 + 32) & 1023);
    ldB((it + 2) & 3, (s0 + 64) & 1023);

    f32x4 accS[2] = {fz, fz};
#pragma unroll
    for (int mt = 0; mt < 2; mt++)
#pragma unroll
      for (int kc = 0; kc < 2; kc++)
        accS[mt] = MFMA16(Kf[it & 1][mt * 2 + kc], bQ[kc], accS[mt]);

#pragma unroll
    for (int mt = 0; mt < 2; mt++) {
      bf16x4 pb;
#pragma unroll
      for (int r = 0; r < 4; r++) {
        float p = __builtin_amdgcn_exp2f(
            (accS[mt][r] + (float)Bf[it & 3][mt * 4 + r]) * SC);
        pb[r] = (bf16)p;
      }
      *(bf16x4*)(&Pl[wid][n15][mt * 16 + qd * 4]) = pb;
    }
    bf16x8 bP = *(const bf16x8*)(&Pl[wid][n15][qd * 8]);
    accL = MFMA16(onesv, bP, accL);
#pragma unroll
    for (int dt = 0; dt < 4; dt++) accO[dt] = MFMA16(Vf[it & 1][dt], bP, accO[dt]);
  }

  int bb = bh >> 3, hh = bh & 7;
  float rcp = 1.0f / accL[0];
#pragma unroll
  for (int dt = 0; dt < 4; dt++) {
    bf16x4 ov;
#pragma unroll
    for (int r = 0; r < 4; r++) ov[r] = (bf16)(accO[dt][r] * rcp);
    *(bf16x4*)(att + ((size_t)bb * TT + t0 + n15) * NU + hh * DH + dt * 16 + qd * 4) = ov;
  }
}

__global__ __launch_bounds__(256) void proj_k(const bf16* __restrict__ att,
                                              const bf16* __restrict__ wt,
                                              const float* __restrict__ bo,
                                              float* __restrict__ out) {
  int tid = threadIdx.x, wid = tid >> 6, ln = tid & 63;
  int n15 = ln & 15, qd = ln >> 4;
  int n0 = blockIdx.x * 64, m0 = blockIdx.y * 64;
  int mrow = m0 + wid * 16 + n15;

  const f32x4 fz = {0.f, 0.f, 0.f, 0.f};
  f32x4 acc[4] = {fz, fz, fz, fz};
  for (int k0 = 0; k0 < NU; k0 += 32) {
    bf16x8 a = *(const bf16x8*)(att + (size_t)mrow * NU + k0 + qd * 8);
#pragma unroll
    for (int nt = 0; nt < 4; nt++) {
      bf16x8 b = *(const bf16x8*)(wt + ((size_t)3 * NU + n0 + nt * 16 + n15) * NU +
                                  k0 + qd * 8);
      acc[nt] = MFMA16(a, b, acc[nt]);
    }
  }
#pragma unroll
  for (int nt = 0; nt < 4; nt++) {
    int col = n0 + nt * 16 + n15;
    float bov = bo[col];
#pragma unroll
    for (int r = 0; r < 4; r++) {
      int row = m0 + wid * 16 + qd * 4 + r;
      out[(size_t)row * NU + col] = acc[nt][r] + bov;
    }
  }
}

// ======================= fused cooperative kernel =======================

__global__ __launch_bounds__(256, 2) void fused_k(
    const float* __restrict__ x, const float* __restrict__ pos,
    const float* __restrict__ Wq, const float* __restrict__ bq,
    const float* __restrict__ Wk, const float* __restrict__ bk,
    const float* __restrict__ Wv, const float* __restrict__ bv,
    const float* __restrict__ Wo, const float* __restrict__ bo,
    bf16* __restrict__ xb, bf16* __restrict__ wt, bf16* __restrict__ Qb,
    bf16* __restrict__ Kb, bf16* __restrict__ Vt, bf16* __restrict__ biasF,
    bf16* __restrict__ att, float* __restrict__ out) {
  cg::grid_group grid = cg::this_grid();
  const int tid = threadIdx.x, bid = blockIdx.x;
  const int wid = tid >> 6, ln = tid & 63;
  const int n15 = ln & 15, qd = ln >> 4;
  const f32x4 fz = {0.f, 0.f, 0.f, 0.f};

  // shared by phase C (Qs2: 2*32*72 = 4608 elems) and phase D (Pl: 4*16*40)
  __shared__ __align__(16) bf16 smem[4608];

  // ---------- Phase A: x->bf16 (4 float4/thread) + weight transpose ----------
  {
#pragma unroll
    for (int u = 0; u < 4; u++) {
      int i = (u * 512 + bid) * 256 + tid;
      float4 v = ((const float4*)x)[i];
      bf16x4 o = {(bf16)v.x, (bf16)v.y, (bf16)v.z, (bf16)v.w};
      ((bf16x4*)xb)[i] = o;
    }
    int w = bid >> 7, rem = bid & 127;
    int k0 = (rem >> 1) * 8;
    int n = (rem & 1) * 256 + tid;
    const float* W = (w == 0) ? Wq : (w == 1) ? Wk : (w == 2) ? Wv : Wo;
    bf16x8 wv;
#pragma unroll
    for (int j = 0; j < 8; j++) wv[j] = (bf16)W[(size_t)(k0 + j) * NU + n];
    *(bf16x8*)(wt + ((size_t)w * NU + n) * NU + k0) = wv;
  }
  grid.sync();

  // ---------- Phase B: fused QKV projection (64x64 tile per block) ----------
  {
    int n0 = (bid & 7) * 64, m0 = (bid >> 3) * 64;
    int mrow = m0 + wid * 16 + n15;
    f32x4 acc[3][4];
#pragma unroll
    for (int w = 0; w < 3; w++)
#pragma unroll
      for (int nt = 0; nt < 4; nt++) acc[w][nt] = fz;

    for (int k0 = 0; k0 < NU; k0 += 32) {
      bf16x8 a = *(const bf16x8*)(xb + (size_t)mrow * NU + k0 + qd * 8);
#pragma unroll
      for (int w = 0; w < 3; w++)
#pragma unroll
        for (int nt = 0; nt < 4; nt++) {
          bf16x8 b = *(const bf16x8*)(wt +
              ((size_t)w * NU + n0 + nt * 16 + n15) * NU + k0 + qd * 8);
          acc[w][nt] = MFMA16(a, b, acc[w][nt]);
        }
    }

    int bb = m0 >> 10;
    int tbase = (m0 & 1023) + wid * 16 + qd * 4;
    int hh = n0 >> 6;
#pragma unroll
    for (int nt = 0; nt < 4; nt++) {
      int d = nt * 16 + n15;
      float bqv = bq[n0 + d], bkv = bk[n0 + d], bvv = bv[n0 + d];
      bf16x4 vv;
#pragma unroll
      for (int r = 0; r < 4; r++) {
        int t = tbase + r;
        size_t qk_idx = ((size_t)(bb * NH + hh) * TT + t) * DH + d;
        Qb[qk_idx] = (bf16)(acc[0][nt][r] + bqv);
        Kb[qk_idx] = (bf16)(acc[1][nt][r] + bkv);
        vv[r] = (bf16)(acc[2][nt][r] + bvv);
      }
      *(bf16x4*)(Vt + ((size_t)(bb * NH + hh) * DH + d) * TT + tbase) = vv;
    }
  }
  grid.sync();

  // ---------- Phase C: pos-score GEMM. Block owns t in {2*bid, 2*bid+1}, all s.
  // Q for both t staged once; 16 (tt,sc) units run barrier-free so the
  // nontemporal pos stream (512 KB contiguous per block) pipelines deeply.
  {
    {
      int bh = tid >> 3, dc = (tid & 7) * 8;
#pragma unroll
      for (int tt = 0; tt < 2; tt++) {
        int t = bid * 2 + tt;
        *(bf16x8*)(&smem[(size_t)(tt * 32 + bh) * 72 + dc]) =
            *(const bf16x8*)(Qb + ((size_t)bh * TT + t) * DH + dc);
      }
    }
    __syncthreads();

    bf16x8 bQ2[2][2][2];
#pragma unroll
    for (int tt = 0; tt < 2; tt++)
#pragma unroll
      for (int bht = 0; bht < 2; bht++)
#pragma unroll
        for (int kc = 0; kc < 2; kc++)
          bQ2[tt][bht][kc] = *(const bf16x8*)(
              &smem[(tt * 32 + bht * 16 + n15) * 72 + kc * 32 + qd * 8]);

#pragma unroll
    for (int tt = 0; tt < 2; tt++) {
      int t = bid * 2 + tt;
      int t16 = t >> 4, tin = t & 15;
#pragma unroll 2
      for (int sc = 0; sc < 8; sc++) {
        int sw = sc * 128 + wid * 32;
        f32x4 acc[2][2];
#pragma unroll
        for (int stl = 0; stl < 2; stl++)
#pragma unroll
          for (int bht = 0; bht < 2; bht++) acc[stl][bht] = fz;

#pragma unroll
        for (int stl = 0; stl < 2; stl++) {
          const float* pr =
              pos + ((size_t)t * TT + sw + stl * 16 + n15) * DH + qd * 8;
#pragma unroll
          for (int kc = 0; kc < 2; kc++) {
            f32x4 u = __builtin_nontemporal_load((const f32x4*)(pr + kc * 32));
            f32x4 v2 = __builtin_nontemporal_load((const f32x4*)(pr + kc * 32 + 4));
            bf16x8 aP = {(bf16)u[0], (bf16)u[1], (bf16)u[2], (bf16)u[3],
                         (bf16)v2[0], (bf16)v2[1], (bf16)v2[2], (bf16)v2[3]};
#pragma unroll
            for (int bht = 0; bht < 2; bht++)
              acc[stl][bht] = MFMA16(aP, bQ2[tt][bht][kc], acc[stl][bht]);
          }
        }

        int s32 = sc * 4 + wid;
#pragma unroll
        for (int bht = 0; bht < 2; bht++) {
          bf16x8 ov;
#pragma unroll
          for (int r = 0; r < 4; r++) {
            ov[r] = (bf16)acc[0][bht][r];
            ov[4 + r] = (bf16)acc[1][bht][r];
          }
          *(bf16x8*)(biasF +
                     (((size_t)(bht * 16 + n15) * 64 + t16) * 32 + s32) * 512 +
                     tin * 32 + qd * 8) = ov;
        }
      }
    }
  }
  grid.sync();

  // ---------- Phase D: flash attention (S^T form), one (bh, 64-t) unit/block ----------
  {
    int bh = bid & 31;
    int t0 = (bid >> 5) * 64 + wid * 16;
    const float SC = 0.18033688f;  // log2(e)/8

    bf16* Pl = &smem[wid * 640];  // per-wave [16][40]

    bf16x8 bQ[2];
#pragma unroll
    for (int kc = 0; kc < 2; kc++)
      bQ[kc] = *(const bf16x8*)(Qb + ((size_t)bh * TT + t0 + n15) * DH +
                                kc * 32 + qd * 8);

    const bf16* Kbase = Kb + (size_t)bh * TT * DH;
    const bf16* Vbase = Vt + (size_t)bh * DH * TT;
    const bf16* Fbase = biasF + (((size_t)bh * 64 + (t0 >> 4)) * 32) * 512 +
                        n15 * 32 + qd * 8;

    f32x4 accO[4] = {fz, fz, fz, fz};
    f32x4 accL = fz;
    const bf16 one = (bf16)1.0f;
    const bf16x8 onesv = {one, one, one, one, one, one, one, one};

    bf16x8 Kf[2][4], Vf[2][4];
    bf16x8 Bf[4];

    auto ldKV = [&](int buf, int s0) {
#pragma unroll
      for (int mt = 0; mt < 2; mt++)
#pragma unroll
        for (int kc = 0; kc < 2; kc++)
          Kf[buf][mt * 2 + kc] = *(const bf16x8*)(
              Kbase + (size_t)(s0 + mt * 16 + n15) * DH + kc * 32 + qd * 8);
#pragma unroll
      for (int dt = 0; dt < 4; dt++)
        Vf[buf][dt] =
            *(const bf16x8*)(Vbase + (size_t)(dt * 16 + n15) * TT + s0 + qd * 8);
    };
    auto ldB = [&](int buf, int s0) {
      Bf[buf] = *(const bf16x8*)(Fbase + (size_t)(s0 >> 5) * 512);
    };

    ldB(0, 0);
    ldB(1, 32);
    ldKV(0, 0);

#pragma unroll 4
    for (int it = 0; it < 32; it++) {
      int s0 = it * 32;
      ldKV((it + 1) & 1, (s0 + 32) & 1023);  // dist-1 prefetch (wraps harmlessly)
      ldB((it + 2) & 3, (s0 + 64) & 1023);   // dist-2 prefetch

      f32x4 accS[2] = {fz, fz};
#pragma unroll
      for (int mt = 0; mt < 2; mt++)
#pragma unroll
        for (int kc = 0; kc < 2; kc++)
          accS[mt] = MFMA16(Kf[it & 1][mt * 2 + kc], bQ[kc], accS[mt]);

#pragma unroll
      for (int mt = 0; mt < 2; mt++) {
        bf16x4 pb;
#pragma unroll
        for (int r = 0; r < 4; r++) {
          float p = __builtin_amdgcn_exp2f(
              (accS[mt][r] + (float)Bf[it & 3][mt * 4 + r]) * SC);
          pb[r] = (bf16)p;
        }
        *(bf16x4*)(&Pl[n15 * 40 + mt * 16 + qd * 4]) = pb;
      }
      bf16x8 bP = *(const bf16x8*)(&Pl[n15 * 40 + qd * 8]);
      accL = MFMA16(onesv, bP, accL);
#pragma unroll
      for (int dt = 0; dt < 4; dt++)
        accO[dt] = MFMA16(Vf[it & 1][dt], bP, accO[dt]);
    }

    int bb = bh >> 3, hh = bh & 7;
    float rcp = 1.0f / accL[0];
#pragma unroll
    for (int dt = 0; dt < 4; dt++) {
      bf16x4 ov;
#pragma unroll
      for (int r = 0; r < 4; r++) ov[r] = (bf16)(accO[dt][r] * rcp);
      *(bf16x4*)(att + ((size_t)bb * TT + t0 + n15) * NU + hh * DH + dt * 16 +
                 qd * 4) = ov;
    }
  }
  grid.sync();

  // ---------- Phase E: output projection ----------
  {
    int n0 = (bid & 7) * 64, m0 = (bid >> 3) * 64;
    int mrow = m0 + wid * 16 + n15;
    f32x4 acc[4] = {fz, fz, fz, fz};
    for (int k0 = 0; k0 < NU; k0 += 32) {
      bf16x8 a = *(const bf16x8*)(att + (size_t)mrow * NU + k0 + qd * 8);
#pragma unroll
      for (int nt = 0; nt < 4; nt++) {
        bf16x8 b = *(const bf16x8*)(wt + ((size_t)3 * NU + n0 + nt * 16 + n15) * NU +
                                    k0 + qd * 8);
        acc[nt] = MFMA16(a, b, acc[nt]);
      }
    }
#pragma unroll
    for (int nt = 0; nt < 4; nt++) {
      int col = n0 + nt * 16 + n15;
      float bov = bo[col];
#pragma unroll
      for (int r = 0; r < 4; r++) {
        int row = m0 + wid * 16 + qd * 4 + r;
        out[(size_t)row * NU + col] = acc[nt][r] + bov;
      }
    }
  }
}

// ======================= launcher =======================

extern "C" void kernel_launch(void* const* d_in, const int* in_sizes, int n_in,
                              void* d_out, int out_size, void* d_ws, size_t ws_size,
                              hipStream_t stream) {
  const float* x = (const float*)d_in[0];
  const float* pos = (const float*)d_in[1];
  const float* Wq = (const float*)d_in[3];
  const float* bq = (const float*)d_in[4];
  const float* Wk = (const float*)d_in[5];
  const float* bk = (const float*)d_in[6];
  const float* Wv = (const float*)d_in[7];
  const float* bv = (const float*)d_in[8];
  const float* Wo = (const float*)d_in[9];
  const float* bo = (const float*)d_in[10];
  float* out = (float*)d_out;

  char* ws = (char*)d_ws;
  bf16* xb = (bf16*)(ws);                          // 4 MB
  bf16* wt = (bf16*)(ws + ((size_t)4 << 20));      // 2 MB  [4][512][512]
  bf16* Qb = (bf16*)(ws + ((size_t)6 << 20));      // 4 MB  [bh][t][d]
  bf16* Kb = (bf16*)(ws + ((size_t)10 << 20));     // 4 MB  [bh][t][d]
  bf16* Vt = (bf16*)(ws + ((size_t)14 << 20));     // 4 MB  [bh][d][t]
  bf16* att = (bf16*)(ws + ((size_t)18 << 20));    // 4 MB  [row][unit]
  bf16* biasF = (bf16*)(ws + ((size_t)22 << 20));  // 64 MB frag-packed tiles

  void* args[] = {&x,  &pos, &Wq, &bq, &Wk, &bk,    &Wv,  &bv, &Wo,
                  &bo, &xb,  &wt, &Qb, &Kb, &Vt, &biasF, &att, &out};
  hipError_t err = hipLaunchCooperativeKernel((void*)fused_k, dim3(512),
                                              dim3(256), args, 0, stream);
  if (err != hipSuccess) {
    // fallback: verified 6-kernel pipeline
    cvtx_k<<<2048, 256, 0, stream>>>(x, xb);
    wtrans_k<<<dim3(2, 64, 4), 256, 0, stream>>>(Wq, Wk, Wv, Wo, wt);
    qkv_k<<<dim3(8, 64), 256, 0, stream>>>(xb, wt, bq, bk, bv, Qb, Kb, Vt);
    pos_gemm_k<<<dim3(8, 1024), 256, 0, stream>>>(pos, Qb, biasF);
    flash_k<<<dim3(32, 16), 256, 0, stream>>>(Qb, Kb, Vt, biasF, att);
    proj_k<<<dim3(8, 64), 256, 0, stream>>>(att, wt, bo, out);
  }
}

// Round 2
// 534.389 us; speedup vs baseline: 1.4940x; 1.4940x over previous
//
#include <hip/hip_runtime.h>

// MultiHeadSelfAttention: B=4 T=1024 H=8 D=64 N_UNITS=512, fp32 in/out.
// R5: split pipeline (cooperative fusion abandoned — R4 showed 97% stall at
// 8 waves/CU; short high-occupancy blocks win). Changes vs R3 baseline:
//  - flash split over s-halves (grid 32x16x2 -> 16 waves/CU on the
//    latency-bound kernel) + combine_k (partials add; softmax has no
//    running max so halves combine by addition).
//  - qkv/proj n-split to 32 cols (grid 1024, 4 blocks/CU).
//  - cvtx+wtrans merged into prep_k.
//  - pos_gemm untouched (near its BW roofline by model).
// Fragment layouts (16x16x32_bf16): A/B = 8 contig k at row lane&15,
// k-offset (lane>>4)*8 ; C/D: col=lane&15, row=(lane>>4)*4+reg.

#define TT 1024
#define DH 64
#define NH 8
#define NU 512

typedef __bf16 bf16;
typedef bf16 bf16x8 __attribute__((ext_vector_type(8)));
typedef bf16 bf16x4 __attribute__((ext_vector_type(4)));
typedef float f32x4 __attribute__((ext_vector_type(4)));

#define MFMA16(a, b, c) __builtin_amdgcn_mfma_f32_16x16x32_bf16(a, b, c, 0, 0, 0)

// ---------------- prep: x -> bf16 + weights -> bf16 transposed [w][n][k] ----------------
__global__ __launch_bounds__(256) void prep_k(const float* __restrict__ x,
                                              const float* __restrict__ Wq,
                                              const float* __restrict__ Wk,
                                              const float* __restrict__ Wv,
                                              const float* __restrict__ Wo,
                                              bf16* __restrict__ xb,
                                              bf16* __restrict__ wt) {
  int bid = blockIdx.x, tid = threadIdx.x;
  // cvtx part: 2048 blocks x 256 thr x 16B
  {
    int i = bid * 256 + tid;
    float4 v = ((const float4*)x)[i];
    bf16x4 o = {(bf16)v.x, (bf16)v.y, (bf16)v.z, (bf16)v.w};
    ((bf16x4*)xb)[i] = o;
  }
  // wtrans part: 512 units spread over blocks bid%4==0
  if ((bid & 3) == 0) {
    int u = bid >> 2;               // 0..511
    int w = u >> 7, rem = u & 127;  // 4 weights x (64 k0 x 2 n-halves)
    int k0 = (rem >> 1) * 8;
    int n = (rem & 1) * 256 + tid;
    const float* W = (w == 0) ? Wq : (w == 1) ? Wk : (w == 2) ? Wv : Wo;
    bf16x8 v;
#pragma unroll
    for (int j = 0; j < 8; j++) v[j] = (bf16)W[(size_t)(k0 + j) * NU + n];
    *(bf16x8*)(wt + ((size_t)w * NU + n) * NU + k0) = v;
  }
}

// ---------------- fused QKV projection GEMM (n-tile 32, grid 16x64) ----------------
__global__ __launch_bounds__(256) void qkv_k(
    const bf16* __restrict__ xb, const bf16* __restrict__ wt,
    const float* __restrict__ bq, const float* __restrict__ bk,
    const float* __restrict__ bv, bf16* __restrict__ Qb, bf16* __restrict__ Kb,
    bf16* __restrict__ Vt) {
  int tid = threadIdx.x, wid = tid >> 6, ln = tid & 63;
  int n15 = ln & 15, qd = ln >> 4;
  int n0 = blockIdx.x * 32, m0 = blockIdx.y * 64;
  int mrow = m0 + wid * 16 + n15;

  const f32x4 fz = {0.f, 0.f, 0.f, 0.f};
  f32x4 acc[3][2];
#pragma unroll
  for (int w = 0; w < 3; w++)
#pragma unroll
    for (int nt = 0; nt < 2; nt++) acc[w][nt] = fz;

  for (int k0 = 0; k0 < NU; k0 += 32) {
    bf16x8 a = *(const bf16x8*)(xb + (size_t)mrow * NU + k0 + qd * 8);
#pragma unroll
    for (int w = 0; w < 3; w++)
#pragma unroll
      for (int nt = 0; nt < 2; nt++) {
        bf16x8 b = *(const bf16x8*)(wt + ((size_t)w * NU + n0 + nt * 16 + n15) * NU +
                                    k0 + qd * 8);
        acc[w][nt] = MFMA16(a, b, acc[w][nt]);
      }
  }

  int bb = m0 >> 10;
  int tbase = (m0 & 1023) + wid * 16 + qd * 4;
  int hh = n0 >> 6;  // two n-tiles per head
#pragma unroll
  for (int nt = 0; nt < 2; nt++) {
    int col = n0 + nt * 16 + n15;   // global unit column
    int d = (n0 & 63) + nt * 16 + n15;  // within-head dim (no carry: <64)
    float bqv = bq[col], bkv = bk[col], bvv = bv[col];
    bf16x4 vv;
#pragma unroll
    for (int r = 0; r < 4; r++) {
      int t = tbase + r;
      size_t qk_idx = ((size_t)(bb * NH + hh) * TT + t) * DH + d;
      Qb[qk_idx] = (bf16)(acc[0][nt][r] + bqv);
      Kb[qk_idx] = (bf16)(acc[1][nt][r] + bkv);
      vv[r] = (bf16)(acc[2][nt][r] + bvv);
    }
    *(bf16x4*)(Vt + ((size_t)(bb * NH + hh) * DH + d) * TT + tbase) = vv;
  }
}

// ---------------- pos-score GEMM (transposed: M=s, N=bh) — unchanged ----------------
// bias[bh][t][s] = Q[bh,t,:] . pos_k[t,s,:], stored fragment-packed:
// biasF tile (bh, t16=t/16, s32=s/32) = 512 elems; elem (tin, qd, mt, r) at
// tin*32 + qd*8 + mt*4 + r  ->  value bias[bh][t16*16+tin][s32*32+mt*16+qd*4+r]
__global__ __launch_bounds__(256) void pos_gemm_k(const float* __restrict__ pos,
                                                  const bf16* __restrict__ Qb,
                                                  bf16* __restrict__ biasF) {
  int tid = threadIdx.x, wid = tid >> 6, ln = tid & 63;
  int n15 = ln & 15, qd = ln >> 4;
  int t = blockIdx.y;
  int s0b = blockIdx.x * 128;

  __shared__ bf16 Qs[32 * 72];  // [bh][d], stride 72
  {
    int bh = tid >> 3, dc = (tid & 7) * 8;
    *(bf16x8*)(&Qs[bh * 72 + dc]) =
        *(const bf16x8*)(Qb + ((size_t)bh * TT + t) * DH + dc);
  }
  __syncthreads();

  // Q as B-operand: B[n=bh][k=d]
  bf16x8 bQ[2][2];
#pragma unroll
  for (int bht = 0; bht < 2; bht++)
#pragma unroll
    for (int kc = 0; kc < 2; kc++)
      bQ[bht][kc] = *(const bf16x8*)(&Qs[(bht * 16 + n15) * 72 + kc * 32 + qd * 8]);

  const f32x4 fz = {0.f, 0.f, 0.f, 0.f};
  f32x4 acc[2][2];  // [stl][bht]
#pragma unroll
  for (int stl = 0; stl < 2; stl++)
#pragma unroll
    for (int bht = 0; bht < 2; bht++) acc[stl][bht] = fz;

  int sw = s0b + wid * 32;  // this wave's 32-s slice
#pragma unroll
  for (int stl = 0; stl < 2; stl++) {
    // A-frag: A[m = s-row = n15][k = d = kc*32 + qd*8 + j]
    const float* pr = pos + ((size_t)t * TT + sw + stl * 16 + n15) * DH + qd * 8;
#pragma unroll
    for (int kc = 0; kc < 2; kc++) {
      f32x4 u = __builtin_nontemporal_load((const f32x4*)(pr + kc * 32));
      f32x4 v = __builtin_nontemporal_load((const f32x4*)(pr + kc * 32 + 4));
      bf16x8 aP = {(bf16)u[0], (bf16)u[1], (bf16)u[2], (bf16)u[3],
                   (bf16)v[0], (bf16)v[1], (bf16)v[2], (bf16)v[3]};
#pragma unroll
      for (int bht = 0; bht < 2; bht++)
        acc[stl][bht] = MFMA16(aP, bQ[bht][kc], acc[stl][bht]);
    }
  }

  // store: lane (qd,n15) -> 16 B per bht: [stl=0 r-quad][stl=1 r-quad]
  int t16 = t >> 4, tin = t & 15, s32 = (s0b >> 5) + wid;
#pragma unroll
  for (int bht = 0; bht < 2; bht++) {
    bf16x8 ov;
#pragma unroll
    for (int r = 0; r < 4; r++) {
      ov[r] = (bf16)acc[0][bht][r];
      ov[4 + r] = (bf16)acc[1][bht][r];
    }
    *(bf16x8*)(biasF +
               (((size_t)(bht * 16 + n15) * 64 + t16) * 32 + s32) * 512 +
               tin * 32 + qd * 8) = ov;
  }
}

// ---------------- flash attention partial (S^T form, s-half split) ----------------
// grid (32 bh, 16 tb, 2 sh). Each block: 4 waves x 16 t, s in [sh*512, sh*512+512).
// Partials: partO[sh][bh][t][d] fp32 (coalesced 64B granules), partL[sh][bh][t].
__global__ __launch_bounds__(256) void flash_part_k(const bf16* __restrict__ Qb,
                                                    const bf16* __restrict__ Kb,
                                                    const bf16* __restrict__ Vt,
                                                    const bf16* __restrict__ biasF,
                                                    float* __restrict__ partO,
                                                    float* __restrict__ partL) {
  int tid = threadIdx.x, wid = tid >> 6, ln = tid & 63;
  int n15 = ln & 15, qd = ln >> 4;
  int bh = blockIdx.x;
  int t0 = blockIdx.y * 64 + wid * 16;
  int sh = blockIdx.z;
  int sB = sh * 512;
  const float SC = 0.18033688f;  // log2(e)/8

  __shared__ bf16 Pl[4][16][40];  // per-wave P^T tile [t][s], stride 40

  // Q as B-operand: B[n=t][k=d]
  bf16x8 bQ[2];
#pragma unroll
  for (int kc = 0; kc < 2; kc++)
    bQ[kc] = *(const bf16x8*)(Qb + ((size_t)bh * TT + t0 + n15) * DH + kc * 32 + qd * 8);

  const bf16* Kbase = Kb + (size_t)bh * TT * DH;
  const bf16* Vbase = Vt + (size_t)bh * DH * TT;
  const bf16* Fbase = biasF + (((size_t)bh * 64 + (t0 >> 4)) * 32) * 512 +
                      n15 * 32 + qd * 8;  // + s32*512

  const f32x4 fz = {0.f, 0.f, 0.f, 0.f};
  f32x4 accO[4] = {fz, fz, fz, fz};
  f32x4 accL = fz;
  const bf16 one = (bf16)1.0f;
  const bf16x8 onesv = {one, one, one, one, one, one, one, one};

  bf16x8 Kf[2][4], Vf[2][4];
  bf16x8 Bf[4];

  auto ldKV = [&](int buf, int s0) {
#pragma unroll
    for (int mt = 0; mt < 2; mt++)
#pragma unroll
      for (int kc = 0; kc < 2; kc++)
        Kf[buf][mt * 2 + kc] =
            *(const bf16x8*)(Kbase + (size_t)(s0 + mt * 16 + n15) * DH + kc * 32 + qd * 8);
#pragma unroll
    for (int dt = 0; dt < 4; dt++)
      Vf[buf][dt] = *(const bf16x8*)(Vbase + (size_t)(dt * 16 + n15) * TT + s0 + qd * 8);
  };
  auto ldB = [&](int buf, int s0) {
    Bf[buf] = *(const bf16x8*)(Fbase + (size_t)(s0 >> 5) * 512);
  };

  ldB(0, sB);
  ldB(1, sB + 32);
  ldKV(0, sB);

#pragma unroll 4
  for (int it = 0; it < 16; it++) {
    int s0 = sB + it * 32;
    ldKV((it + 1) & 1, sB + (((it + 1) * 32) & 511));  // dist-1 prefetch (wraps in half)
    ldB((it + 2) & 3, sB + (((it + 2) * 32) & 511));   // dist-2 prefetch

    f32x4 accS[2] = {fz, fz};  // S^T: row=s-in-tile, col=t
#pragma unroll
    for (int mt = 0; mt < 2; mt++)
#pragma unroll
      for (int kc = 0; kc < 2; kc++)
        accS[mt] = MFMA16(Kf[it & 1][mt * 2 + kc], bQ[kc], accS[mt]);

#pragma unroll
    for (int mt = 0; mt < 2; mt++) {
      bf16x4 pb;
#pragma unroll
      for (int r = 0; r < 4; r++) {
        float p = __builtin_amdgcn_exp2f(
            (accS[mt][r] + (float)Bf[it & 3][mt * 4 + r]) * SC);
        pb[r] = (bf16)p;
      }
      *(bf16x4*)(&Pl[wid][n15][mt * 16 + qd * 4]) = pb;
    }
    bf16x8 bP = *(const bf16x8*)(&Pl[wid][n15][qd * 8]);  // B[n=t][k=s]
    accL = MFMA16(onesv, bP, accL);
#pragma unroll
    for (int dt = 0; dt < 4; dt++) accO[dt] = MFMA16(Vf[it & 1][dt], bP, accO[dt]);
  }

  // store partials: lane (n15,qd) owns t = t0+n15, d = dt*16+qd*4..+3
  int t = t0 + n15;
  float* po = partO + (((size_t)sh * 32 + bh) * TT + t) * DH + qd * 4;
#pragma unroll
  for (int dt = 0; dt < 4; dt++) *(f32x4*)(po + dt * 16) = accO[dt];
  if (qd == 0) partL[((size_t)sh * 32 + bh) * TT + t] = accL[0];
}

// ---------------- combine partials -> att ----------------
__global__ __launch_bounds__(256) void combine_k(const float* __restrict__ partO,
                                                 const float* __restrict__ partL,
                                                 bf16* __restrict__ att) {
  int idx = blockIdx.x * 256 + threadIdx.x;  // 32768 = 32 bh x 1024 t
  int bh = idx >> 10, t = idx & 1023;
  const float* pa = partO + ((size_t)bh * TT + t) * DH;
  const float* pb = partO + (((size_t)32 + bh) * TT + t) * DH;
  float rcp = 1.0f / (partL[(size_t)bh * TT + t] + partL[((size_t)32 + bh) * TT + t]);
  int bb = bh >> 3, hh = bh & 7;
  bf16* ao = att + ((size_t)bb * TT + t) * NU + hh * DH;
#pragma unroll
  for (int j = 0; j < 16; j++) {
    f32x4 a = *(const f32x4*)(pa + j * 4);
    f32x4 b = *(const f32x4*)(pb + j * 4);
    bf16x4 ov;
#pragma unroll
    for (int r = 0; r < 4; r++) ov[r] = (bf16)((a[r] + b[r]) * rcp);
    *(bf16x4*)(ao + j * 4) = ov;
  }
}

// ---------------- output projection (n-tile 32, grid 16x64) ----------------
__global__ __launch_bounds__(256) void proj_k(const bf16* __restrict__ att,
                                              const bf16* __restrict__ wt,
                                              const float* __restrict__ bo,
                                              float* __restrict__ out) {
  int tid = threadIdx.x, wid = tid >> 6, ln = tid & 63;
  int n15 = ln & 15, qd = ln >> 4;
  int n0 = blockIdx.x * 32, m0 = blockIdx.y * 64;
  int mrow = m0 + wid * 16 + n15;

  const f32x4 fz = {0.f, 0.f, 0.f, 0.f};
  f32x4 acc[2] = {fz, fz};
  for (int k0 = 0; k0 < NU; k0 += 32) {
    bf16x8 a = *(const bf16x8*)(att + (size_t)mrow * NU + k0 + qd * 8);
#pragma unroll
    for (int nt = 0; nt < 2; nt++) {
      bf16x8 b = *(const bf16x8*)(wt + ((size_t)3 * NU + n0 + nt * 16 + n15) * NU +
                                  k0 + qd * 8);
      acc[nt] = MFMA16(a, b, acc[nt]);
    }
  }
#pragma unroll
  for (int nt = 0; nt < 2; nt++) {
    int col = n0 + nt * 16 + n15;
    float bov = bo[col];
#pragma unroll
    for (int r = 0; r < 4; r++) {
      int row = m0 + wid * 16 + qd * 4 + r;
      out[(size_t)row * NU + col] = acc[nt][r] + bov;
    }
  }
}

extern "C" void kernel_launch(void* const* d_in, const int* in_sizes, int n_in,
                              void* d_out, int out_size, void* d_ws, size_t ws_size,
                              hipStream_t stream) {
  const float* x = (const float*)d_in[0];
  const float* pos = (const float*)d_in[1];
  const float* Wq = (const float*)d_in[3];
  const float* bq = (const float*)d_in[4];
  const float* Wk = (const float*)d_in[5];
  const float* bk = (const float*)d_in[6];
  const float* Wv = (const float*)d_in[7];
  const float* bv = (const float*)d_in[8];
  const float* Wo = (const float*)d_in[9];
  const float* bo = (const float*)d_in[10];
  float* out = (float*)d_out;

  char* ws = (char*)d_ws;
  bf16* xb = (bf16*)(ws);                          // 4 MB
  bf16* wt = (bf16*)(ws + ((size_t)4 << 20));      // 2 MB  [4][512][512]
  bf16* Qb = (bf16*)(ws + ((size_t)6 << 20));      // 4 MB  [bh][t][d]
  bf16* Kb = (bf16*)(ws + ((size_t)10 << 20));     // 4 MB  [bh][t][d]
  bf16* Vt = (bf16*)(ws + ((size_t)14 << 20));     // 4 MB  [bh][d][t]
  bf16* att = (bf16*)(ws + ((size_t)18 << 20));    // 4 MB  [row][unit]
  bf16* biasF = (bf16*)(ws + ((size_t)22 << 20));  // 64 MB frag-packed tiles
  float* partO = (float*)(ws + ((size_t)88 << 20));  // 16.78 MB [sh][bh][t][d]
  float* partL = (float*)(ws + ((size_t)106 << 20)); // 256 KB  [sh][bh][t]

  prep_k<<<2048, 256, 0, stream>>>(x, Wq, Wk, Wv, Wo, xb, wt);
  qkv_k<<<dim3(16, 64), 256, 0, stream>>>(xb, wt, bq, bk, bv, Qb, Kb, Vt);
  pos_gemm_k<<<dim3(8, 1024), 256, 0, stream>>>(pos, Qb, biasF);
  flash_part_k<<<dim3(32, 16, 2), 256, 0, stream>>>(Qb, Kb, Vt, biasF, partO, partL);
  combine_k<<<128, 256, 0, stream>>>(partO, partL, att);
  proj_k<<<dim3(16, 64), 256, 0, stream>>>(att, wt, bo, out);
}

// Round 3
// 527.658 us; speedup vs baseline: 1.5130x; 1.0128x over previous
//
#include <hip/hip_runtime.h>

// MultiHeadSelfAttention: B=4 T=1024 H=8 D=64 N_UNITS=512, fp32 in/out.
// R6: budget model (3 rounds evidence): dur = kernels + ~320us fixed in-window
// harness poison fills. Kernel budget ~207us vs ~130us roofline sum; slack is
// flash's serial per-iteration chain at 2 waves/SIMD. Changes vs R3 baseline:
//  - flash: s-step 32 -> 64, fully double-buffered (Kf/Vf/Bf x2), 18 MFMA +
//    18 in-flight 16B loads per iter, 16 iters. Grid pins 2 waves/SIMD, so
//    VGPR up to 256 are free: __launch_bounds__(256,2), est ~215 VGPR.
//  - R5's s-half split + combine REVERTED (measured +7us: partO round-trip
//    ate the occupancy gain). qkv/proj back to R3 64-col form.
//  - prep_k keeps cvtx+wtrans merged (one less launch).
//  - pos_gemm untouched (near its 43us pos-read BW floor).
// Fragment layouts (16x16x32_bf16): A/B = 8 contig k at row lane&15,
// k-offset (lane>>4)*8 ; C/D: col=lane&15, row=(lane>>4)*4+reg.

#define TT 1024
#define DH 64
#define NH 8
#define NU 512

typedef __bf16 bf16;
typedef bf16 bf16x8 __attribute__((ext_vector_type(8)));
typedef bf16 bf16x4 __attribute__((ext_vector_type(4)));
typedef float f32x4 __attribute__((ext_vector_type(4)));

#define MFMA16(a, b, c) __builtin_amdgcn_mfma_f32_16x16x32_bf16(a, b, c, 0, 0, 0)

// ---------------- prep: x -> bf16 + weights -> bf16 transposed [w][n][k] ----------------
__global__ __launch_bounds__(256) void prep_k(const float* __restrict__ x,
                                              const float* __restrict__ Wq,
                                              const float* __restrict__ Wk,
                                              const float* __restrict__ Wv,
                                              const float* __restrict__ Wo,
                                              bf16* __restrict__ xb,
                                              bf16* __restrict__ wt) {
  int bid = blockIdx.x, tid = threadIdx.x;
  // cvtx part: 2048 blocks x 256 thr x 16B
  {
    int i = bid * 256 + tid;
    float4 v = ((const float4*)x)[i];
    bf16x4 o = {(bf16)v.x, (bf16)v.y, (bf16)v.z, (bf16)v.w};
    ((bf16x4*)xb)[i] = o;
  }
  // wtrans part: 512 units spread over blocks bid%4==0
  if ((bid & 3) == 0) {
    int u = bid >> 2;               // 0..511
    int w = u >> 7, rem = u & 127;  // 4 weights x (64 k0 x 2 n-halves)
    int k0 = (rem >> 1) * 8;
    int n = (rem & 1) * 256 + tid;
    const float* W = (w == 0) ? Wq : (w == 1) ? Wk : (w == 2) ? Wv : Wo;
    bf16x8 v;
#pragma unroll
    for (int j = 0; j < 8; j++) v[j] = (bf16)W[(size_t)(k0 + j) * NU + n];
    *(bf16x8*)(wt + ((size_t)w * NU + n) * NU + k0) = v;
  }
}

// ---------------- fused QKV projection GEMM (64x64 tile, grid 8x64) ----------------
__global__ __launch_bounds__(256) void qkv_k(
    const bf16* __restrict__ xb, const bf16* __restrict__ wt,
    const float* __restrict__ bq, const float* __restrict__ bk,
    const float* __restrict__ bv, bf16* __restrict__ Qb, bf16* __restrict__ Kb,
    bf16* __restrict__ Vt) {
  int tid = threadIdx.x, wid = tid >> 6, ln = tid & 63;
  int n15 = ln & 15, qd = ln >> 4;
  int n0 = blockIdx.x * 64, m0 = blockIdx.y * 64;
  int mrow = m0 + wid * 16 + n15;

  const f32x4 fz = {0.f, 0.f, 0.f, 0.f};
  f32x4 acc[3][4];
#pragma unroll
  for (int w = 0; w < 3; w++)
#pragma unroll
    for (int nt = 0; nt < 4; nt++) acc[w][nt] = fz;

  for (int k0 = 0; k0 < NU; k0 += 32) {
    bf16x8 a = *(const bf16x8*)(xb + (size_t)mrow * NU + k0 + qd * 8);
#pragma unroll
    for (int w = 0; w < 3; w++)
#pragma unroll
      for (int nt = 0; nt < 4; nt++) {
        bf16x8 b = *(const bf16x8*)(wt + ((size_t)w * NU + n0 + nt * 16 + n15) * NU +
                                    k0 + qd * 8);
        acc[w][nt] = MFMA16(a, b, acc[w][nt]);
      }
  }

  int bb = m0 >> 10;
  int tbase = (m0 & 1023) + wid * 16 + qd * 4;
  int hh = n0 >> 6;
#pragma unroll
  for (int nt = 0; nt < 4; nt++) {
    int d = nt * 16 + n15;
    float bqv = bq[n0 + d], bkv = bk[n0 + d], bvv = bv[n0 + d];
    bf16x4 vv;
#pragma unroll
    for (int r = 0; r < 4; r++) {
      int t = tbase + r;
      size_t qk_idx = ((size_t)(bb * NH + hh) * TT + t) * DH + d;
      Qb[qk_idx] = (bf16)(acc[0][nt][r] + bqv);
      Kb[qk_idx] = (bf16)(acc[1][nt][r] + bkv);
      vv[r] = (bf16)(acc[2][nt][r] + bvv);
    }
    *(bf16x4*)(Vt + ((size_t)(bb * NH + hh) * DH + d) * TT + tbase) = vv;
  }
}

// ---------------- pos-score GEMM (transposed: M=s, N=bh) — unchanged ----------------
// bias[bh][t][s] = Q[bh,t,:] . pos_k[t,s,:], stored fragment-packed:
// biasF tile (bh, t16=t/16, s32=s/32) = 512 elems; elem (tin, qd, mt, r) at
// tin*32 + qd*8 + mt*4 + r  ->  value bias[bh][t16*16+tin][s32*32+mt*16+qd*4+r]
__global__ __launch_bounds__(256) void pos_gemm_k(const float* __restrict__ pos,
                                                  const bf16* __restrict__ Qb,
                                                  bf16* __restrict__ biasF) {
  int tid = threadIdx.x, wid = tid >> 6, ln = tid & 63;
  int n15 = ln & 15, qd = ln >> 4;
  int t = blockIdx.y;
  int s0b = blockIdx.x * 128;

  __shared__ bf16 Qs[32 * 72];  // [bh][d], stride 72
  {
    int bh = tid >> 3, dc = (tid & 7) * 8;
    *(bf16x8*)(&Qs[bh * 72 + dc]) =
        *(const bf16x8*)(Qb + ((size_t)bh * TT + t) * DH + dc);
  }
  __syncthreads();

  // Q as B-operand: B[n=bh][k=d]
  bf16x8 bQ[2][2];
#pragma unroll
  for (int bht = 0; bht < 2; bht++)
#pragma unroll
    for (int kc = 0; kc < 2; kc++)
      bQ[bht][kc] = *(const bf16x8*)(&Qs[(bht * 16 + n15) * 72 + kc * 32 + qd * 8]);

  const f32x4 fz = {0.f, 0.f, 0.f, 0.f};
  f32x4 acc[2][2];  // [stl][bht]
#pragma unroll
  for (int stl = 0; stl < 2; stl++)
#pragma unroll
    for (int bht = 0; bht < 2; bht++) acc[stl][bht] = fz;

  int sw = s0b + wid * 32;  // this wave's 32-s slice
#pragma unroll
  for (int stl = 0; stl < 2; stl++) {
    // A-frag: A[m = s-row = n15][k = d = kc*32 + qd*8 + j]
    const float* pr = pos + ((size_t)t * TT + sw + stl * 16 + n15) * DH + qd * 8;
#pragma unroll
    for (int kc = 0; kc < 2; kc++) {
      f32x4 u = __builtin_nontemporal_load((const f32x4*)(pr + kc * 32));
      f32x4 v = __builtin_nontemporal_load((const f32x4*)(pr + kc * 32 + 4));
      bf16x8 aP = {(bf16)u[0], (bf16)u[1], (bf16)u[2], (bf16)u[3],
                   (bf16)v[0], (bf16)v[1], (bf16)v[2], (bf16)v[3]};
#pragma unroll
      for (int bht = 0; bht < 2; bht++)
        acc[stl][bht] = MFMA16(aP, bQ[bht][kc], acc[stl][bht]);
    }
  }

  // store: lane (qd,n15) -> 16 B per bht: [stl=0 r-quad][stl=1 r-quad]
  int t16 = t >> 4, tin = t & 15, s32 = (s0b >> 5) + wid;
#pragma unroll
  for (int bht = 0; bht < 2; bht++) {
    bf16x8 ov;
#pragma unroll
    for (int r = 0; r < 4; r++) {
      ov[r] = (bf16)acc[0][bht][r];
      ov[4 + r] = (bf16)acc[1][bht][r];
    }
    *(bf16x8*)(biasF +
               (((size_t)(bht * 16 + n15) * 64 + t16) * 32 + s32) * 512 +
               tin * 32 + qd * 8) = ov;
  }
}

// ---------------- flash attention (S^T form, s-step 64, deep ILP) ----------------
// grid (32 bh, 16 tb); 4 waves x 16 t each. Per iter: 64 s = 4 m-tiles;
// 18x16B loads in flight (K 8, V 8, bias 2), 18 MFMA, 16 exp. 16 iters.
__global__ __launch_bounds__(256, 2) void flash_k(const bf16* __restrict__ Qb,
                                                  const bf16* __restrict__ Kb,
                                                  const bf16* __restrict__ Vt,
                                                  const bf16* __restrict__ biasF,
                                                  bf16* __restrict__ att) {
  int tid = threadIdx.x, wid = tid >> 6, ln = tid & 63;
  int n15 = ln & 15, qd = ln >> 4;
  int bh = blockIdx.x;
  int t0 = blockIdx.y * 64 + wid * 16;
  const float SC = 0.18033688f;  // log2(e)/8

  __shared__ bf16 Pl[4][16][72];  // per-wave P^T tile [t][s(64)+pad]

  // Q as B-operand: B[n=t][k=d]
  bf16x8 bQ[2];
#pragma unroll
  for (int kc = 0; kc < 2; kc++)
    bQ[kc] = *(const bf16x8*)(Qb + ((size_t)bh * TT + t0 + n15) * DH + kc * 32 + qd * 8);

  const bf16* Kbase = Kb + (size_t)bh * TT * DH;
  const bf16* Vbase = Vt + (size_t)bh * DH * TT;
  const bf16* Fbase = biasF + (((size_t)bh * 64 + (t0 >> 4)) * 32) * 512 +
                      n15 * 32 + qd * 8;  // + s32*512

  const f32x4 fz = {0.f, 0.f, 0.f, 0.f};
  f32x4 accO[4] = {fz, fz, fz, fz};
  f32x4 accL = fz;
  const bf16 one = (bf16)1.0f;
  const bf16x8 onesv = {one, one, one, one, one, one, one, one};

  bf16x8 Kf[2][8], Vf[2][8];  // [buf][mt*2+kc] / [buf][dt*2+sc]
  bf16x8 Bf[2][2];            // [buf][sc]

  auto ldKV = [&](int buf, int s0) {
#pragma unroll
    for (int mt = 0; mt < 4; mt++)
#pragma unroll
      for (int kc = 0; kc < 2; kc++)
        Kf[buf][mt * 2 + kc] =
            *(const bf16x8*)(Kbase + (size_t)(s0 + mt * 16 + n15) * DH + kc * 32 + qd * 8);
#pragma unroll
    for (int dt = 0; dt < 4; dt++)
#pragma unroll
      for (int sc = 0; sc < 2; sc++)
        Vf[buf][dt * 2 + sc] =
            *(const bf16x8*)(Vbase + (size_t)(dt * 16 + n15) * TT + s0 + sc * 32 + qd * 8);
  };
  auto ldB = [&](int buf, int s0) {
#pragma unroll
    for (int sc = 0; sc < 2; sc++)
      Bf[buf][sc] = *(const bf16x8*)(Fbase + (size_t)((s0 >> 5) + sc) * 512);
  };

  ldKV(0, 0);
  ldB(0, 0);

#pragma unroll 2
  for (int it = 0; it < 16; it++) {
    int s0 = it * 64;
    int cb = it & 1, nb = (it + 1) & 1;
    ldKV(nb, (s0 + 64) & 1023);  // dist-1 prefetch (wraps harmlessly at it=15)
    ldB(nb, (s0 + 64) & 1023);

    f32x4 accS[4] = {fz, fz, fz, fz};  // S^T: 4 m-tiles of 16 s x 16 t
#pragma unroll
    for (int mt = 0; mt < 4; mt++)
#pragma unroll
      for (int kc = 0; kc < 2; kc++)
        accS[mt] = MFMA16(Kf[cb][mt * 2 + kc], bQ[kc], accS[mt]);

#pragma unroll
    for (int mt = 0; mt < 4; mt++) {
      bf16x4 pb;
#pragma unroll
      for (int r = 0; r < 4; r++) {
        float p = __builtin_amdgcn_exp2f(
            (accS[mt][r] + (float)Bf[cb][mt >> 1][(mt & 1) * 4 + r]) * SC);
        pb[r] = (bf16)p;
      }
      *(bf16x4*)(&Pl[wid][n15][mt * 16 + qd * 4]) = pb;
    }

#pragma unroll
    for (int sc = 0; sc < 2; sc++) {
      bf16x8 bP = *(const bf16x8*)(&Pl[wid][n15][sc * 32 + qd * 8]);  // B[n=t][k=s]
      accL = MFMA16(onesv, bP, accL);
#pragma unroll
      for (int dt = 0; dt < 4; dt++)
        accO[dt] = MFMA16(Vf[cb][dt * 2 + sc], bP, accO[dt]);
    }
  }

  int bb = bh >> 3, hh = bh & 7;
  float rcp = 1.0f / accL[0];  // denom for t = t0+n15 (all rows identical)
#pragma unroll
  for (int dt = 0; dt < 4; dt++) {
    bf16x4 ov;
#pragma unroll
    for (int r = 0; r < 4; r++) ov[r] = (bf16)(accO[dt][r] * rcp);
    *(bf16x4*)(att + ((size_t)bb * TT + t0 + n15) * NU + hh * DH + dt * 16 + qd * 4) = ov;
  }
}

// ---------------- output projection (64x64 tile, grid 8x64) ----------------
__global__ __launch_bounds__(256) void proj_k(const bf16* __restrict__ att,
                                              const bf16* __restrict__ wt,
                                              const float* __restrict__ bo,
                                              float* __restrict__ out) {
  int tid = threadIdx.x, wid = tid >> 6, ln = tid & 63;
  int n15 = ln & 15, qd = ln >> 4;
  int n0 = blockIdx.x * 64, m0 = blockIdx.y * 64;
  int mrow = m0 + wid * 16 + n15;

  const f32x4 fz = {0.f, 0.f, 0.f, 0.f};
  f32x4 acc[4] = {fz, fz, fz, fz};
  for (int k0 = 0; k0 < NU; k0 += 32) {
    bf16x8 a = *(const bf16x8*)(att + (size_t)mrow * NU + k0 + qd * 8);
#pragma unroll
    for (int nt = 0; nt < 4; nt++) {
      bf16x8 b = *(const bf16x8*)(wt + ((size_t)3 * NU + n0 + nt * 16 + n15) * NU +
                                  k0 + qd * 8);
      acc[nt] = MFMA16(a, b, acc[nt]);
    }
  }
#pragma unroll
  for (int nt = 0; nt < 4; nt++) {
    int col = n0 + nt * 16 + n15;
    float bov = bo[col];
#pragma unroll
    for (int r = 0; r < 4; r++) {
      int row = m0 + wid * 16 + qd * 4 + r;
      out[(size_t)row * NU + col] = acc[nt][r] + bov;
    }
  }
}

extern "C" void kernel_launch(void* const* d_in, const int* in_sizes, int n_in,
                              void* d_out, int out_size, void* d_ws, size_t ws_size,
                              hipStream_t stream) {
  const float* x = (const float*)d_in[0];
  const float* pos = (const float*)d_in[1];
  const float* Wq = (const float*)d_in[3];
  const float* bq = (const float*)d_in[4];
  const float* Wk = (const float*)d_in[5];
  const float* bk = (const float*)d_in[6];
  const float* Wv = (const float*)d_in[7];
  const float* bv = (const float*)d_in[8];
  const float* Wo = (const float*)d_in[9];
  const float* bo = (const float*)d_in[10];
  float* out = (float*)d_out;

  char* ws = (char*)d_ws;
  bf16* xb = (bf16*)(ws);                          // 4 MB
  bf16* wt = (bf16*)(ws + ((size_t)4 << 20));      // 2 MB  [4][512][512]
  bf16* Qb = (bf16*)(ws + ((size_t)6 << 20));      // 4 MB  [bh][t][d]
  bf16* Kb = (bf16*)(ws + ((size_t)10 << 20));     // 4 MB  [bh][t][d]
  bf16* Vt = (bf16*)(ws + ((size_t)14 << 20));     // 4 MB  [bh][d][t]
  bf16* att = (bf16*)(ws + ((size_t)18 << 20));    // 4 MB  [row][unit]
  bf16* biasF = (bf16*)(ws + ((size_t)22 << 20));  // 64 MB frag-packed tiles

  prep_k<<<2048, 256, 0, stream>>>(x, Wq, Wk, Wv, Wo, xb, wt);
  qkv_k<<<dim3(8, 64), 256, 0, stream>>>(xb, wt, bq, bk, bv, Qb, Kb, Vt);
  pos_gemm_k<<<dim3(8, 1024), 256, 0, stream>>>(pos, Qb, biasF);
  flash_k<<<dim3(32, 16), 256, 0, stream>>>(Qb, Kb, Vt, biasF, att);
  proj_k<<<dim3(8, 64), 256, 0, stream>>>(att, wt, bo, out);
}